// Round 9
// baseline (206.044 us; speedup 1.0000x reference)
//
#include <hip/hip_runtime.h>
#include <math.h>

#define NANCH 896
#define MAXD 64
#define NS 14   // 896 / 64 max slots per lane

// ---------- slot-pair compare-exchange for bitonic (compile-time JS) ----------
#define SLOTSTAGE(JS, K)                                                     \
    {                                                                        \
        _Pragma("unroll")                                                    \
        for (int s = 0; s < 8; ++s) if ((s & (JS)) == 0) {                   \
            const int s2 = s | (JS);                                         \
            const bool up = (((s << 6) & (K)) == 0);                         \
            unsigned long long a = ik[s], b = ik[s2];                        \
            unsigned long long mn = (a < b) ? a : b;                         \
            unsigned long long mx = (a < b) ? b : a;                         \
            ik[s] = up ? mn : mx; ik[s2] = up ? mx : mn;                     \
        }                                                                    \
    }

__device__ __forceinline__ float rdlane(float v, int sl) {
    return __uint_as_float((unsigned)__builtin_amdgcn_readlane(__float_as_int(v), sl));
}

// =============== sorted-order NMS (nact <= 512) ===============
// Sort active anchors ONCE by (score desc, pos asc) via a 512-wide bitonic
// network on u64 keys (pure __shfl_xor + C compares). The per-iteration
// argmax then becomes find-first-alive: 1 ballot + ffs + slot cursor
// (~20 cyc vs ~350 for the 6-stage shfl butterfly). Wave-uniform broadcasts
// use v_readlane (scalar) instead of ds_bpermute.
__device__ __forceinline__ void sorted_nms(
    const int lane, const int nact,
    const float4* __restrict__ cbox, const float* __restrict__ cscore,
    const unsigned short* __restrict__ cidx, float* __restrict__ sdet,
    const float* __restrict__ rb, const float* __restrict__ anchors,
    const float m0, const float m1, const float m3,
    const float m4, const float m5, const float m7,
    const float hf, const float wf, float* __restrict__ ob)
{
    const float inv = 1.f / 128.f;

    // ---- build INVERTED keys (ascending sort of ~key == descending key).
    //      key = (bits(score)<<10) | (1023-pos): u64 order == (score desc,
    //      pos asc) exactly; pad/invalid -> key 0 -> ~key huge -> sorts last.
    unsigned long long ik[8];
#pragma unroll
    for (int s = 0; s < 8; ++s) {
        const int p = s * 64 + lane;
        unsigned long long key = 0ull;
        if (p < nact) {
            key = ((unsigned long long)__float_as_uint(cscore[p]) << 10)
                | (unsigned long long)(1023 - p);
        }
        ik[s] = ~key;
    }

    // ---- bitonic ascending sort of 512 u64 over (slot,lane): element
    //      index i = s*64+lane. Runtime k/j loops (code-size); slot stages
    //      (j>=64) explicit with literal JS so ik[] indexing stays static.
    for (int k = 2; k <= 512; k <<= 1) {
        if (k == 128)      { SLOTSTAGE(1, 128) }
        else if (k == 256) { SLOTSTAGE(2, 256) SLOTSTAGE(1, 256) }
        else if (k == 512) { SLOTSTAGE(4, 512) SLOTSTAGE(2, 512) SLOTSTAGE(1, 512) }
        const int jstart = ((k >> 1) > 32) ? 32 : (k >> 1);
        for (int j = jstart; j > 0; j >>= 1) {
#pragma unroll
            for (int s = 0; s < 8; ++s) {
                unsigned long long a = ik[s];
                unsigned plo = (unsigned)__shfl_xor((int)(unsigned)a, j, 64);
                unsigned phi = (unsigned)__shfl_xor((int)(unsigned)(a >> 32), j, 64);
                unsigned long long b = ((unsigned long long)phi << 32) | plo;
                const bool up    = ((((s << 6) | lane) & k) == 0);
                const bool lower = ((lane & j) == 0);
                unsigned long long mn = (a < b) ? a : b;
                unsigned long long mx = (a < b) ? b : a;
                ik[s] = ((up == lower) ? mn : mx);
            }
        }
    }

    // ---- payload gather into sorted-slot registers (one-time) ----
    unsigned long long skey[8];
    float sb0[8], sb1[8], sb2[8], sb3[8], sar[8], sw[8];
    int sorig[8];
#pragma unroll
    for (int s = 0; s < 8; ++s) {
        const unsigned long long key = ~ik[s];
        skey[s] = key;
        const int pc = (key != 0ull) ? (1023 - (int)(key & 1023ull)) : 0;
        float4 bb = cbox[pc];
        sb0[s] = bb.x; sb1[s] = bb.y; sb2[s] = bb.z; sb3[s] = bb.w;
        sar[s] = fmaxf(bb.z - bb.x, 0.f) * fmaxf(bb.w - bb.y, 0.f);
        sorig[s] = (int)cidx[pc];
        sw[s] = __uint_as_float((unsigned)(key >> 10));   // exact score bits
    }

    const bool isx = (lane < 16) && ((0x555Au >> lane) & 1u);

    int cur = 0, iter = 0;
    while (true) {
        // ---- find-first-alive in sorted order (replaces argmax) ----
        unsigned am = 0;
#pragma unroll
        for (int s = 0; s < 8; ++s) am |= (skey[s] != 0ull) ? (1u << s) : 0u;
        unsigned long long m = 0ull;
        while (cur < 8) {
            m = __ballot(((am >> cur) & 1u) != 0u);
            if (m != 0ull) break;
            ++cur;
        }
        if (m == 0ull) {                       // exhausted -> zero fill
            int n = (MAXD - iter) * 17;
            float* op = ob + iter * 17;
            for (int e = lane; e < n; e += 64) op[e] = 0.f;
            break;
        }
        const int bl = (int)__ffsll((long long)m) - 1;

        // ---- best values: per-lane select of slot `cur`, readlane(bl) ----
        float o0 = sb0[0], o1 = sb1[0], o2 = sb2[0], o3 = sb3[0],
              oa = sar[0], os = sw[0];
#pragma unroll
        for (int s = 1; s < 8; ++s) {
            const bool c = (cur == s);
            o0 = c ? sb0[s] : o0; o1 = c ? sb1[s] : o1;
            o2 = c ? sb2[s] : o2; o3 = c ? sb3[s] : o3;
            oa = c ? sar[s] : oa; os = c ? sw[s]  : os;
        }
        const float bby0 = rdlane(o0, bl), bbx0 = rdlane(o1, bl);
        const float bby1 = rdlane(o2, bl), bbx1 = rdlane(o3, bl);
        const float a1   = rdlane(oa, bl);
        const float bv   = rdlane(os, bl);

        float acc[16];
#pragma unroll
        for (int c = 0; c < 16; ++c) acc[c] = 0.f;
        float wsum = 0.f;
        bool anyov = false;

        // ---- overlap scan over 8 sorted slots (proven arithmetic) ----
#pragma unroll
        for (int j = 0; j < 8; ++j) {
            float yA = fmaxf(bby0, sb0[j]);
            float xA = fmaxf(bbx0, sb1[j]);
            float yB = fminf(bby1, sb2[j]);
            float xB = fminf(bbx1, sb3[j]);
            float inter = fmaxf(yB - yA, 0.f) * fmaxf(xB - xA, 0.f);
            if (inter > 0.f) {
                float iou = inter / fmaxf(a1 + sar[j] - inter, 1e-6f);
                if (iou > 0.3f && skey[j] != 0ull) {
                    anyov = true;
                    const float wj = sw[j];
                    skey[j] = 0ull;            // removal
                    wsum += wj;
                    acc[0] += sb0[j] * wj; acc[1] += sb1[j] * wj;
                    acc[2] += sb2[j] * wj; acc[3] += sb3[j] * wj;
                    const int orig = sorig[j];
                    float4 an = *(const float4*)(anchors + orig * 4);
                    const float* rp = rb + orig * 16;
                    float4 r1 = *(const float4*)(rp + 4);
                    float4 r2 = *(const float4*)(rp + 8);
                    float4 r3 = *(const float4*)(rp + 12);
                    acc[4]  += (r1.x * inv * an.z + an.x) * wj;
                    acc[5]  += (r1.y * inv * an.w + an.y) * wj;
                    acc[6]  += (r1.z * inv * an.z + an.x) * wj;
                    acc[7]  += (r1.w * inv * an.w + an.y) * wj;
                    acc[8]  += (r2.x * inv * an.z + an.x) * wj;
                    acc[9]  += (r2.y * inv * an.w + an.y) * wj;
                    acc[10] += (r2.z * inv * an.z + an.x) * wj;
                    acc[11] += (r2.w * inv * an.w + an.y) * wj;
                    acc[12] += (r3.x * inv * an.z + an.x) * wj;
                    acc[13] += (r3.y * inv * an.w + an.y) * wj;
                    acc[14] += (r3.z * inv * an.z + an.x) * wj;
                    acc[15] += (r3.w * inv * an.w + an.y) * wj;
                }
            }
        }

        const unsigned long long mm = __ballot(anyov);
        const bool stuck = (mm == 0ull);

        float q, dnm;
        if (stuck) {
            q = 0.f; dnm = 1e-6f;              // reference: blend of zeros
        } else if (__popcll(mm) == 1) {
            // FAST PATH: single contributor; readlane (uniform src) replaces
            // shfl -- bit-exact (others hold +0, x+0==x).
            const int src = (int)__ffsll((long long)mm) - 1;
            float t = rdlane(acc[0], src);
#pragma unroll
            for (int c = 1; c < 16; ++c) {
                const float tc = rdlane(acc[c], src);
                t = (lane == c) ? tc : t;
            }
            q   = t;
            dnm = fmaxf(rdlane(wsum, src), 1e-6f);
        } else {
            // general path (rare): identical butterfly tree as proven rounds
#pragma unroll
            for (int s2 = 32; s2 >= 1; s2 >>= 1) {
                wsum += __shfl_xor(wsum, s2, 64);
#pragma unroll
                for (int c = 0; c < 16; ++c) acc[c] += __shfl_xor(acc[c], s2, 64);
            }
            float t = acc[0];
#pragma unroll
            for (int c2 = 1; c2 < 16; ++c2) t = (lane == c2) ? acc[c2] : t;
            q = t; dnm = fmaxf(wsum, 1e-6f);
        }

        q = q / dnm;                                   // ONE divide per lane
        const float p = __shfl(q, lane ^ 1, 64);       // x/y partner channel
        const float detc = (lane >= 16) ? bv
                         : (isx ? (q * m0 + p * m1 + m3) * wf
                                : (p * m4 + q * m5 + m7) * hf);

        if (stuck) {
            if (lane < 17) sdet[lane] = detc;
            int n = (MAXD - iter) * 17;
            float* op = ob + iter * 17;
            int c = lane % 17;
            for (int e = lane; e < n; e += 64) {
                op[e] = sdet[c];
                c += 13; if (c >= 17) c -= 17;         // (e+64) % 17
            }
            break;
        } else {
            if (lane < 17) ob[iter * 17 + lane] = detc;
            ++iter;
            if (iter == MAXD) break;
        }
    }
}

// =============== R5-proven fallback loop (nact > 512, ~never) ===============
template <int NSLOT>
__device__ __forceinline__ void nms_loop(
    const int lane, const int nact,
    const float4* __restrict__ cbox, const float* __restrict__ cscore,
    const unsigned short* __restrict__ cidx, float* __restrict__ sdet,
    const float* __restrict__ rb, const float* __restrict__ anchors,
    const float m0, const float m1, const float m3,
    const float m4, const float m5, const float m7,
    const float hf, const float wf, float* __restrict__ ob)
{
    const float inv = 1.f / 128.f;
    float cb0[NSLOT], cb1[NSLOT], cb2[NSLOT], cb3[NSLOT], car[NSLOT], rem[NSLOT];
    int   corig[NSLOT];
#pragma unroll
    for (int k = 0; k < NSLOT; ++k) {
        int p = k * 64 + lane;
        bool v = (p < nact);
        int pc = v ? p : 0;
        float4 bb = cbox[pc];
        cb0[k] = bb.x; cb1[k] = bb.y; cb2[k] = bb.z; cb3[k] = bb.w;
        car[k] = fmaxf(bb.z - bb.x, 0.f) * fmaxf(bb.w - bb.y, 0.f);
        corig[k] = (int)cidx[pc];
        rem[k] = v ? cscore[pc] : -1.f;
    }
    const bool isx = (lane < 16) && ((0x555Au >> lane) & 1u);
    int iter = 0;
    while (true) {
        float bv = -2.f; int bi = 1 << 30;
#pragma unroll
        for (int j = 0; j < NSLOT; ++j) {
            if (rem[j] > bv) { bv = rem[j]; bi = j * 64 + lane; }
        }
#pragma unroll
        for (int s2 = 32; s2 >= 1; s2 >>= 1) {
            float ov = __shfl_xor(bv, s2, 64);
            int   oi = __shfl_xor(bi, s2, 64);
            if (ov > bv || (ov == bv && oi < bi)) { bv = ov; bi = oi; }
        }
        if (bv <= 0.f) {
            int n = (MAXD - iter) * 17;
            float* op = ob + iter * 17;
            for (int e = lane; e < n; e += 64) op[e] = 0.f;
            break;
        }
        float4 bb = cbox[bi];
        const float bby0 = bb.x, bbx0 = bb.y, bby1 = bb.z, bbx1 = bb.w;
        const float a1 = fmaxf(bby1 - bby0, 0.f) * fmaxf(bbx1 - bbx0, 0.f);
        float acc[16];
#pragma unroll
        for (int c = 0; c < 16; ++c) acc[c] = 0.f;
        float wsum = 0.f;
        bool anyov = false;
#pragma unroll
        for (int j = 0; j < NSLOT; ++j) {
            float yA = fmaxf(bby0, cb0[j]);
            float xA = fmaxf(bbx0, cb1[j]);
            float yB = fminf(bby1, cb2[j]);
            float xB = fminf(bbx1, cb3[j]);
            float inter = fmaxf(yB - yA, 0.f) * fmaxf(xB - xA, 0.f);
            if (inter > 0.f) {
                float iou = inter / fmaxf(a1 + car[j] - inter, 1e-6f);
                if (iou > 0.3f && rem[j] > 0.f) {
                    anyov = true;
                    float wj = rem[j];
                    rem[j] = -1.f;
                    wsum += wj;
                    acc[0] += cb0[j] * wj; acc[1] += cb1[j] * wj;
                    acc[2] += cb2[j] * wj; acc[3] += cb3[j] * wj;
                    const int orig = corig[j];
                    float4 an = *(const float4*)(anchors + orig * 4);
                    const float* rp = rb + orig * 16;
                    float4 r1 = *(const float4*)(rp + 4);
                    float4 r2 = *(const float4*)(rp + 8);
                    float4 r3 = *(const float4*)(rp + 12);
                    acc[4]  += (r1.x * inv * an.z + an.x) * wj;
                    acc[5]  += (r1.y * inv * an.w + an.y) * wj;
                    acc[6]  += (r1.z * inv * an.z + an.x) * wj;
                    acc[7]  += (r1.w * inv * an.w + an.y) * wj;
                    acc[8]  += (r2.x * inv * an.z + an.x) * wj;
                    acc[9]  += (r2.y * inv * an.w + an.y) * wj;
                    acc[10] += (r2.z * inv * an.z + an.x) * wj;
                    acc[11] += (r2.w * inv * an.w + an.y) * wj;
                    acc[12] += (r3.x * inv * an.z + an.x) * wj;
                    acc[13] += (r3.y * inv * an.w + an.y) * wj;
                    acc[14] += (r3.z * inv * an.z + an.x) * wj;
                    acc[15] += (r3.w * inv * an.w + an.y) * wj;
                }
            }
        }
        const unsigned long long mm = __ballot(anyov);
        const bool stuck = (mm == 0ull);
        float q, dnm;
        if (stuck) {
            q = 0.f; dnm = 1e-6f;
        } else if (__popcll(mm) == 1) {
            const int src = (int)__ffsll((long long)mm) - 1;
            float t = __shfl(acc[0], src, 64);
#pragma unroll
            for (int c = 1; c < 16; ++c) {
                float tc = __shfl(acc[c], src, 64);
                t = (lane == c) ? tc : t;
            }
            q   = t;
            dnm = fmaxf(__shfl(wsum, src, 64), 1e-6f);
        } else {
#pragma unroll
            for (int s2 = 32; s2 >= 1; s2 >>= 1) {
                wsum += __shfl_xor(wsum, s2, 64);
#pragma unroll
                for (int c = 0; c < 16; ++c) acc[c] += __shfl_xor(acc[c], s2, 64);
            }
            float t = acc[0];
#pragma unroll
            for (int c2 = 1; c2 < 16; ++c2) t = (lane == c2) ? acc[c2] : t;
            q = t; dnm = fmaxf(wsum, 1e-6f);
        }
        q = q / dnm;
        const float p = __shfl(q, lane ^ 1, 64);
        const float detc = (lane >= 16) ? bv
                         : (isx ? (q * m0 + p * m1 + m3) * wf
                                : (p * m4 + q * m5 + m7) * hf);
        if (stuck) {
            if (lane < 17) sdet[lane] = detc;
            int n = (MAXD - iter) * 17;
            float* op = ob + iter * 17;
            int c = lane % 17;
            for (int e = lane; e < n; e += 64) {
                op[e] = sdet[c];
                c += 13; if (c >= 17) c -= 17;
            }
            break;
        } else {
            if (lane < 17) ob[iter * 17 + lane] = detc;
            ++iter;
            if (iter == MAXD) break;
        }
    }
}

// ONE WAVE per batch. Setup identical to proven R4/R5.
__global__ __launch_bounds__(64, 2) void blaze_wave_kernel(
    const float* __restrict__ raw_boxes,   // [B,896,16]
    const float* __restrict__ raw_scores,  // [B,896]
    const float* __restrict__ anchors,     // [896,4]
    const float* __restrict__ tmat,        // [B,8]
    const int* __restrict__ hptr,
    const int* __restrict__ wptr,
    float* __restrict__ out,               // [B,64,17]
    int B)
{
    __shared__ float4 cbox[NANCH];
    __shared__ float  cscore[NANCH];
    __shared__ unsigned short cidx[NANCH];
    __shared__ float  sdet[17];

    const int lane = threadIdx.x;
    const int b    = blockIdx.x;
    if (b >= B) return;

    const float* rb = raw_boxes  + (size_t)b * (NANCH * 16);
    const float* rs = raw_scores + (size_t)b * NANCH;
    const float inv = 1.f / 128.f;

    const float* M = tmat + (size_t)b * 8;
    const float m0 = M[0], m1 = M[1], m3 = M[3];
    const float m4 = M[4], m5 = M[5], m7 = M[7];
    const float hf = (float)(*hptr);
    const float wf = (float)(*wptr);

    float xv[NS];
#pragma unroll
    for (int j = 0; j < NS; ++j) xv[j] = rs[lane + 64 * j];

    bool  act[NS];
    float4 r0v[NS], anv[NS];
#pragma unroll
    for (int j = 0; j < NS; ++j) {
        act[j] = (xv[j] >= 0.f);           // sigmoid>=0.5 <=> x>=0 (exact)
        const int a2 = act[j] ? (lane + 64 * j) : 0;
        r0v[j] = *(const float4*)(rb + a2 * 16);
        anv[j] = *(const float4*)(anchors + a2 * 4);
    }

    float sv[NS];
#pragma unroll
    for (int j = 0; j < NS; ++j) {
        float x = fminf(fmaxf(xv[j], -100.f), 100.f);
        sv[j] = 1.f / (1.f + expf(-x));
    }

    int base = 0;
#pragma unroll
    for (int j = 0; j < NS; ++j) {
        float xc = r0v[j].x * inv * anv[j].z + anv[j].x;
        float yc = r0v[j].y * inv * anv[j].w + anv[j].y;
        float ww = r0v[j].z * inv * anv[j].z;
        float hh = r0v[j].w * inv * anv[j].w;
        float y0 = yc - hh * 0.5f, x0 = xc - ww * 0.5f;
        float y1 = yc + hh * 0.5f, x1 = xc + ww * 0.5f;
        unsigned long long m = __ballot(act[j]);
        int pos = base + __popcll(m & ((1ull << lane) - 1ull));
        if (act[j]) {
            cbox[pos]   = make_float4(y0, x0, y1, x1);
            cscore[pos] = sv[j];
            cidx[pos]   = (unsigned short)(lane + 64 * j);
        }
        base += __popcll(m);
    }
    const int nact = base;
    const int nsc  = (nact + 63) >> 6;

    float* ob = out + (size_t)b * (MAXD * 17);

    if (nsc <= 8)
        sorted_nms(lane, nact, cbox, cscore, cidx, sdet, rb, anchors,
                   m0, m1, m3, m4, m5, m7, hf, wf, ob);
    else if (nsc <= 10)
        nms_loop<10>(lane, nact, cbox, cscore, cidx, sdet, rb, anchors,
                     m0, m1, m3, m4, m5, m7, hf, wf, ob);
    else
        nms_loop<14>(lane, nact, cbox, cscore, cidx, sdet, rb, anchors,
                     m0, m1, m3, m4, m5, m7, hf, wf, ob);
}

extern "C" void kernel_launch(void* const* d_in, const int* in_sizes, int n_in,
                              void* d_out, int out_size, void* d_ws, size_t ws_size,
                              hipStream_t stream) {
    (void)n_in; (void)out_size; (void)d_ws; (void)ws_size;
    const float* raw_boxes  = (const float*)d_in[0];
    const float* raw_scores = (const float*)d_in[1];
    const float* anchors    = (const float*)d_in[2];
    const float* tmat       = (const float*)d_in[3];
    const int*   hptr       = (const int*)d_in[4];
    const int*   wptr       = (const int*)d_in[5];
    float* out = (float*)d_out;

    const int B = in_sizes[0] / (NANCH * 16);
    blaze_wave_kernel<<<B, 64, 0, stream>>>(raw_boxes, raw_scores, anchors,
                                            tmat, hptr, wptr, out, B);
}

// Round 10
// 188.458 us; speedup vs baseline: 1.0933x; 1.0933x over previous
//
#include <hip/hip_runtime.h>
#include <math.h>

#define NANCH 896
#define MAXD 64
#define NS 14   // 896 / 64 max slots per lane

// ---- DPP lexicographic-max step: moves (bv,bi) with IDENTICAL ctrl and
//      combines with the exact tie-break compare. Native float/int only --
//      no bit-packing anywhere (R3's failure class excluded by construction).
//      bound_ctrl=1 zero-injection is benign: 0 only survives when all
//      genuine values are negative, where the bv<=0 exit fires identically.
template <int CTRL>
__device__ __forceinline__ void dpp_amax_step(float& bv, int& bi) {
    const float ov = __uint_as_float((unsigned)__builtin_amdgcn_update_dpp(
        0, (int)__float_as_uint(bv), CTRL, 0xF, 0xF, true));
    const int oi = __builtin_amdgcn_update_dpp(0, bi, CTRL, 0xF, 0xF, true);
    if (ov > bv || (ov == bv && oi < bi)) { bv = ov; bi = oi; }
}

// Templated NMS loop (R5-proven structure). Round-10 delta: the argmax
// wave-reduction runs on the VALU DPP pipe (row_shr 1/2/4/8 + row_bcast
// 15/31, result in lane 63, readlane out) instead of 6 dependent
// ds_bpermute-pair stages -- removing ~250 cyc of DS-pipe latency from the
// serial per-iteration chain.
template <int NSLOT>
__device__ __forceinline__ void nms_loop(
    const int lane, const int nact,
    const float4* __restrict__ cbox, const float* __restrict__ cscore,
    const unsigned short* __restrict__ cidx, float* __restrict__ sdet,
    const float* __restrict__ rb, const float* __restrict__ anchors,
    const float m0, const float m1, const float m3,
    const float m4, const float m5, const float m7,
    const float hf, const float wf, float* __restrict__ ob)
{
    const float inv = 1.f / 128.f;

    // ---- readback compacted entries into per-lane slot registers ----
    float cb0[NSLOT], cb1[NSLOT], cb2[NSLOT], cb3[NSLOT], car[NSLOT], rem[NSLOT];
    int   corig[NSLOT];
#pragma unroll
    for (int k = 0; k < NSLOT; ++k) {
        int p = k * 64 + lane;
        bool v = (p < nact);
        int pc = v ? p : 0;
        float4 bb = cbox[pc];
        cb0[k] = bb.x; cb1[k] = bb.y; cb2[k] = bb.z; cb3[k] = bb.w;
        car[k] = fmaxf(bb.z - bb.x, 0.f) * fmaxf(bb.w - bb.y, 0.f);
        corig[k] = (int)cidx[pc];
        rem[k] = v ? cscore[pc] : -1.f;
    }

    // x-channels: {1,3,4,6,8,10,12,14} -> bitmask 0x555A; partner = c^1
    const bool isx = (lane < 16) && ((0x555Au >> lane) & 1u);

    int iter = 0;
    while (true) {
        // ---- per-lane slot argmax (straight-line, proven) ----
        float bv = -2.f; int bi = 1 << 30;
#pragma unroll
        for (int j = 0; j < NSLOT; ++j) {
            if (rem[j] > bv) { bv = rem[j]; bi = j * 64 + lane; }
        }
        // ---- wave argmax via DPP (VALU pipe; exact total-order reduce) ----
        dpp_amax_step<0x111>(bv, bi);   // row_shr:1
        dpp_amax_step<0x112>(bv, bi);   // row_shr:2
        dpp_amax_step<0x114>(bv, bi);   // row_shr:4
        dpp_amax_step<0x118>(bv, bi);   // row_shr:8
        dpp_amax_step<0x142>(bv, bi);   // row_bcast:15
        dpp_amax_step<0x143>(bv, bi);   // row_bcast:31
        bv = __uint_as_float((unsigned)__builtin_amdgcn_readlane(
                 (int)__float_as_uint(bv), 63));
        bi = __builtin_amdgcn_readlane(bi, 63);

        if (bv <= 0.f) {                    // nothing active left -> zero fill
            int n = (MAXD - iter) * 17;
            float* op = ob + iter * 17;
            for (int e = lane; e < n; e += 64) op[e] = 0.f;
            break;
        }

        // ---- best box: one broadcast LDS read (uniform address) ----
        float4 bb = cbox[bi];
        const float bby0 = bb.x, bbx0 = bb.y, bby1 = bb.z, bbx1 = bb.w;
        const float a1 = fmaxf(bby1 - bby0, 0.f) * fmaxf(bbx1 - bbx0, 0.f);

        float acc[16];
#pragma unroll
        for (int c = 0; c < 16; ++c) acc[c] = 0.f;
        float wsum = 0.f;
        bool anyov = false;

        // ---- overlap scan (straight-line, proven arithmetic/order) ----
#pragma unroll
        for (int j = 0; j < NSLOT; ++j) {
            float yA = fmaxf(bby0, cb0[j]);
            float xA = fmaxf(bbx0, cb1[j]);
            float yB = fminf(bby1, cb2[j]);
            float xB = fminf(bbx1, cb3[j]);
            float inter = fmaxf(yB - yA, 0.f) * fmaxf(xB - xA, 0.f);
            if (inter > 0.f) {
                float iou = inter / fmaxf(a1 + car[j] - inter, 1e-6f);
                if (iou > 0.3f && rem[j] > 0.f) {
                    anyov = true;
                    float wj = rem[j];          // rem>0 ==> rem == score
                    rem[j] = -1.f;
                    wsum += wj;
                    acc[0] += cb0[j] * wj; acc[1] += cb1[j] * wj;
                    acc[2] += cb2[j] * wj; acc[3] += cb3[j] * wj;
                    // keypoints refetched only for overlapped boxes (rare)
                    const int orig = corig[j];
                    float4 an = *(const float4*)(anchors + orig * 4);
                    const float* rp = rb + orig * 16;
                    float4 r1 = *(const float4*)(rp + 4);
                    float4 r2 = *(const float4*)(rp + 8);
                    float4 r3 = *(const float4*)(rp + 12);
                    acc[4]  += (r1.x * inv * an.z + an.x) * wj;
                    acc[5]  += (r1.y * inv * an.w + an.y) * wj;
                    acc[6]  += (r1.z * inv * an.z + an.x) * wj;
                    acc[7]  += (r1.w * inv * an.w + an.y) * wj;
                    acc[8]  += (r2.x * inv * an.z + an.x) * wj;
                    acc[9]  += (r2.y * inv * an.w + an.y) * wj;
                    acc[10] += (r2.z * inv * an.z + an.x) * wj;
                    acc[11] += (r2.w * inv * an.w + an.y) * wj;
                    acc[12] += (r3.x * inv * an.z + an.x) * wj;
                    acc[13] += (r3.y * inv * an.w + an.y) * wj;
                    acc[14] += (r3.z * inv * an.z + an.x) * wj;
                    acc[15] += (r3.w * inv * an.w + an.y) * wj;
                }
            }
        }

        const unsigned long long mm = __ballot(anyov);
        const bool stuck = (mm == 0ull);

        float q, dnm;
        if (stuck) {
            q = 0.f; dnm = 1e-6f;            // reference: blend of zeros
        } else if (__popcll(mm) == 1) {
            // FAST PATH: one contributing lane -> broadcast its partials.
            // Bit-exact vs butterfly: all other lanes hold +0 and x+0==x.
            const int src = (int)__ffsll((long long)mm) - 1;
            float t = __shfl(acc[0], src, 64);
#pragma unroll
            for (int c = 1; c < 16; ++c) {
                float tc = __shfl(acc[c], src, 64);
                t = (lane == c) ? tc : t;
            }
            q   = t;
            dnm = fmaxf(__shfl(wsum, src, 64), 1e-6f);
        } else {
            // general path (rare): identical butterfly tree as prior rounds
#pragma unroll
            for (int s2 = 32; s2 >= 1; s2 >>= 1) {
                wsum += __shfl_xor(wsum, s2, 64);
#pragma unroll
                for (int c = 0; c < 16; ++c) acc[c] += __shfl_xor(acc[c], s2, 64);
            }
            float t = acc[0];
#pragma unroll
            for (int c2 = 1; c2 < 16; ++c2) t = (lane == c2) ? acc[c2] : t;
            q = t; dnm = fmaxf(wsum, 1e-6f);
        }

        q = q / dnm;                                   // ONE divide per lane
        const float p = __shfl(q, lane ^ 1, 64);       // x/y partner channel
        const float detc = (lane >= 16) ? bv
                         : (isx ? (q * m0 + p * m1 + m3) * wf
                                : (p * m4 + q * m5 + m7) * hf);

        if (stuck) {
            // det identical for all remaining rows; lane c holds det[c]
            if (lane < 17) sdet[lane] = detc;
            int n = (MAXD - iter) * 17;
            float* op = ob + iter * 17;
            int c = lane % 17;
            for (int e = lane; e < n; e += 64) {
                op[e] = sdet[c];
                c += 13; if (c >= 17) c -= 17;         // (e+64) % 17
            }
            break;
        } else {
            if (lane < 17) ob[iter * 17 + lane] = detc;
            ++iter;
            if (iter == MAXD) break;
        }
    }
}

// ONE WAVE per batch. Setup (loads, sigmoid, decode, compaction) identical to
// the proven R4/R5 kernel.
__global__ __launch_bounds__(64, 2) void blaze_wave_kernel(
    const float* __restrict__ raw_boxes,   // [B,896,16]
    const float* __restrict__ raw_scores,  // [B,896]
    const float* __restrict__ anchors,     // [896,4]
    const float* __restrict__ tmat,        // [B,8]
    const int* __restrict__ hptr,
    const int* __restrict__ wptr,
    float* __restrict__ out,               // [B,64,17]
    int B)
{
    __shared__ float4 cbox[NANCH];            // compacted decoded boxes
    __shared__ float  cscore[NANCH];          // compacted scores
    __shared__ unsigned short cidx[NANCH];    // compacted -> original anchor idx
    __shared__ float  sdet[17];               // stuck-fill broadcast

    const int lane = threadIdx.x;             // 0..63
    const int b    = blockIdx.x;
    if (b >= B) return;

    const float* rb = raw_boxes  + (size_t)b * (NANCH * 16);
    const float* rs = raw_scores + (size_t)b * NANCH;
    const float inv = 1.f / 128.f;

    // ---- uniform per-batch params in the up-front load burst ----
    const float* M = tmat + (size_t)b * 8;
    const float m0 = M[0], m1 = M[1], m3 = M[3];
    const float m4 = M[4], m5 = M[5], m7 = M[7];
    const float hf = (float)(*hptr);
    const float wf = (float)(*wptr);

    // ---- Phase 1: ALL score loads issued back-to-back ----
    float xv[NS];
#pragma unroll
    for (int j = 0; j < NS; ++j) xv[j] = rs[lane + 64 * j];

    // ---- Phase 2: box/anchor loads gated by SIGN only (sigmoid>=0.5 <=> x>=0;
    //      NaN -> inactive both sides). Inactive lanes alias row 0's line. ----
    bool  act[NS];
    float4 r0v[NS], anv[NS];
#pragma unroll
    for (int j = 0; j < NS; ++j) {
        act[j] = (xv[j] >= 0.f);
        const int a2 = act[j] ? (lane + 64 * j) : 0;
        r0v[j] = *(const float4*)(rb + a2 * 16);
        anv[j] = *(const float4*)(anchors + a2 * 4);
    }

    // ---- sigmoid overlaps the in-flight box loads ----
    float sv[NS];
#pragma unroll
    for (int j = 0; j < NS; ++j) {
        float x = fminf(fmaxf(xv[j], -100.f), 100.f);
        sv[j] = 1.f / (1.f + expf(-x));
    }

    // ---- decode + COMPACT active anchors into LDS (ascending anchor order:
    //      compacted pos is order-isomorphic to anchor index -> exact tiebreak) ----
    int base = 0;
#pragma unroll
    for (int j = 0; j < NS; ++j) {
        float xc = r0v[j].x * inv * anv[j].z + anv[j].x;
        float yc = r0v[j].y * inv * anv[j].w + anv[j].y;
        float ww = r0v[j].z * inv * anv[j].z;
        float hh = r0v[j].w * inv * anv[j].w;
        float y0 = yc - hh * 0.5f, x0 = xc - ww * 0.5f;
        float y1 = yc + hh * 0.5f, x1 = xc + ww * 0.5f;
        unsigned long long m = __ballot(act[j]);
        int pos = base + __popcll(m & ((1ull << lane) - 1ull));
        if (act[j]) {
            cbox[pos]   = make_float4(y0, x0, y1, x1);
            cscore[pos] = sv[j];
            cidx[pos]   = (unsigned short)(lane + 64 * j);
        }
        base += __popcll(m);
    }
    const int nact = base;                  // wave-uniform
    const int nsc  = (nact + 63) >> 6;      // wave-uniform active slot count

    float* ob = out + (size_t)b * (MAXD * 17);

    // ---- one wave-uniform dispatch to a compile-time slot count ----
    if (nsc <= 7)
        nms_loop<7>(lane, nact, cbox, cscore, cidx, sdet, rb, anchors,
                    m0, m1, m3, m4, m5, m7, hf, wf, ob);
    else if (nsc <= 8)
        nms_loop<8>(lane, nact, cbox, cscore, cidx, sdet, rb, anchors,
                    m0, m1, m3, m4, m5, m7, hf, wf, ob);
    else if (nsc <= 10)
        nms_loop<10>(lane, nact, cbox, cscore, cidx, sdet, rb, anchors,
                     m0, m1, m3, m4, m5, m7, hf, wf, ob);
    else
        nms_loop<14>(lane, nact, cbox, cscore, cidx, sdet, rb, anchors,
                     m0, m1, m3, m4, m5, m7, hf, wf, ob);
}

extern "C" void kernel_launch(void* const* d_in, const int* in_sizes, int n_in,
                              void* d_out, int out_size, void* d_ws, size_t ws_size,
                              hipStream_t stream) {
    (void)n_in; (void)out_size; (void)d_ws; (void)ws_size;
    const float* raw_boxes  = (const float*)d_in[0];
    const float* raw_scores = (const float*)d_in[1];
    const float* anchors    = (const float*)d_in[2];
    const float* tmat       = (const float*)d_in[3];
    const int*   hptr       = (const int*)d_in[4];
    const int*   wptr       = (const int*)d_in[5];
    float* out = (float*)d_out;

    const int B = in_sizes[0] / (NANCH * 16);
    blaze_wave_kernel<<<B, 64, 0, stream>>>(raw_boxes, raw_scores, anchors,
                                            tmat, hptr, wptr, out, B);
}

// Round 11
// 187.453 us; speedup vs baseline: 1.0992x; 1.0054x over previous
//
#include <hip/hip_runtime.h>
#include <math.h>

#define NANCH 896
#define MAXD 64
#define NS 14   // 896 / 64 max slots per lane

__device__ __forceinline__ float rdlane(float v, int sl) {
    return __uint_as_float((unsigned)__builtin_amdgcn_readlane(__float_as_int(v), sl));
}

// ---- DPP lexicographic-max step (proven R10): moves (bv,bi) with IDENTICAL
//      ctrl and combines with the exact tie-break compare. bound_ctrl=1
//      zero-injection benign (0 only survives when all values negative ->
//      bv<=0 exit fires identically).
template <int CTRL>
__device__ __forceinline__ void dpp_amax_step(float& bv, int& bi) {
    const float ov = __uint_as_float((unsigned)__builtin_amdgcn_update_dpp(
        0, (int)__float_as_uint(bv), CTRL, 0xF, 0xF, true));
    const int oi = __builtin_amdgcn_update_dpp(0, bi, CTRL, 0xF, 0xF, true);
    if (ov > bv || (ov == bv && oi < bi)) { bv = ov; bi = oi; }
}

// Templated NMS loop (R5/R10-proven structure). Round-11 delta: the serial
// loop now contains ZERO ds_bpermute ops on the common path --
//  (a) argmax reduce: DPP (proven R10)
//  (b) fast-path totals broadcast: v_readlane with wave-uniform src
//      (mechanism proven in passing R9) instead of 16 __shfl
//  (c) x/y partner exchange: DPP quad_perm[1,0,3,2] instead of __shfl(lane^1)
// All values bit-identical to the shfl versions (uniform-source broadcast and
// fixed lane permutation are data-movement only).
template <int NSLOT>
__device__ __forceinline__ void nms_loop(
    const int lane, const int nact,
    const float4* __restrict__ cbox, const float* __restrict__ cscore,
    const unsigned short* __restrict__ cidx, float* __restrict__ sdet,
    const float* __restrict__ rb, const float* __restrict__ anchors,
    const float m0, const float m1, const float m3,
    const float m4, const float m5, const float m7,
    const float hf, const float wf, float* __restrict__ ob)
{
    const float inv = 1.f / 128.f;

    // ---- readback compacted entries into per-lane slot registers ----
    float cb0[NSLOT], cb1[NSLOT], cb2[NSLOT], cb3[NSLOT], car[NSLOT], rem[NSLOT];
    int   corig[NSLOT];
#pragma unroll
    for (int k = 0; k < NSLOT; ++k) {
        int p = k * 64 + lane;
        bool v = (p < nact);
        int pc = v ? p : 0;
        float4 bb = cbox[pc];
        cb0[k] = bb.x; cb1[k] = bb.y; cb2[k] = bb.z; cb3[k] = bb.w;
        car[k] = fmaxf(bb.z - bb.x, 0.f) * fmaxf(bb.w - bb.y, 0.f);
        corig[k] = (int)cidx[pc];
        rem[k] = v ? cscore[pc] : -1.f;
    }

    // x-channels: {1,3,4,6,8,10,12,14} -> bitmask 0x555A; partner = c^1
    const bool isx = (lane < 16) && ((0x555Au >> lane) & 1u);

    int iter = 0;
    while (true) {
        // ---- per-lane slot argmax (straight-line, proven) ----
        float bv = -2.f; int bi = 1 << 30;
#pragma unroll
        for (int j = 0; j < NSLOT; ++j) {
            if (rem[j] > bv) { bv = rem[j]; bi = j * 64 + lane; }
        }
        // ---- wave argmax via DPP (VALU pipe; exact total-order reduce) ----
        dpp_amax_step<0x111>(bv, bi);   // row_shr:1
        dpp_amax_step<0x112>(bv, bi);   // row_shr:2
        dpp_amax_step<0x114>(bv, bi);   // row_shr:4
        dpp_amax_step<0x118>(bv, bi);   // row_shr:8
        dpp_amax_step<0x142>(bv, bi);   // row_bcast:15
        dpp_amax_step<0x143>(bv, bi);   // row_bcast:31
        bv = rdlane(bv, 63);
        bi = __builtin_amdgcn_readlane(bi, 63);

        if (bv <= 0.f) {                    // nothing active left -> zero fill
            int n = (MAXD - iter) * 17;
            float* op = ob + iter * 17;
            for (int e = lane; e < n; e += 64) op[e] = 0.f;
            break;
        }

        // ---- best box: one broadcast LDS read (uniform address) ----
        float4 bb = cbox[bi];
        const float bby0 = bb.x, bbx0 = bb.y, bby1 = bb.z, bbx1 = bb.w;
        const float a1 = fmaxf(bby1 - bby0, 0.f) * fmaxf(bbx1 - bbx0, 0.f);

        float acc[16];
#pragma unroll
        for (int c = 0; c < 16; ++c) acc[c] = 0.f;
        float wsum = 0.f;
        bool anyov = false;

        // ---- overlap scan (straight-line, proven arithmetic/order) ----
#pragma unroll
        for (int j = 0; j < NSLOT; ++j) {
            float yA = fmaxf(bby0, cb0[j]);
            float xA = fmaxf(bbx0, cb1[j]);
            float yB = fminf(bby1, cb2[j]);
            float xB = fminf(bbx1, cb3[j]);
            float inter = fmaxf(yB - yA, 0.f) * fmaxf(xB - xA, 0.f);
            if (inter > 0.f) {
                float iou = inter / fmaxf(a1 + car[j] - inter, 1e-6f);
                if (iou > 0.3f && rem[j] > 0.f) {
                    anyov = true;
                    float wj = rem[j];          // rem>0 ==> rem == score
                    rem[j] = -1.f;
                    wsum += wj;
                    acc[0] += cb0[j] * wj; acc[1] += cb1[j] * wj;
                    acc[2] += cb2[j] * wj; acc[3] += cb3[j] * wj;
                    // keypoints refetched only for overlapped boxes (rare)
                    const int orig = corig[j];
                    float4 an = *(const float4*)(anchors + orig * 4);
                    const float* rp = rb + orig * 16;
                    float4 r1 = *(const float4*)(rp + 4);
                    float4 r2 = *(const float4*)(rp + 8);
                    float4 r3 = *(const float4*)(rp + 12);
                    acc[4]  += (r1.x * inv * an.z + an.x) * wj;
                    acc[5]  += (r1.y * inv * an.w + an.y) * wj;
                    acc[6]  += (r1.z * inv * an.z + an.x) * wj;
                    acc[7]  += (r1.w * inv * an.w + an.y) * wj;
                    acc[8]  += (r2.x * inv * an.z + an.x) * wj;
                    acc[9]  += (r2.y * inv * an.w + an.y) * wj;
                    acc[10] += (r2.z * inv * an.z + an.x) * wj;
                    acc[11] += (r2.w * inv * an.w + an.y) * wj;
                    acc[12] += (r3.x * inv * an.z + an.x) * wj;
                    acc[13] += (r3.y * inv * an.w + an.y) * wj;
                    acc[14] += (r3.z * inv * an.z + an.x) * wj;
                    acc[15] += (r3.w * inv * an.w + an.y) * wj;
                }
            }
        }

        const unsigned long long mm = __ballot(anyov);
        const bool stuck = (mm == 0ull);

        float q, dnm;
        if (stuck) {
            q = 0.f; dnm = 1e-6f;            // reference: blend of zeros
        } else if (__popcll(mm) == 1) {
            // FAST PATH: one contributing lane -> v_readlane broadcast (src is
            // wave-uniform; zero DS ops). Bit-exact: others hold +0, x+0==x.
            const int src = (int)__ffsll((long long)mm) - 1;
            float t = rdlane(acc[0], src);
#pragma unroll
            for (int c = 1; c < 16; ++c) {
                const float tc = rdlane(acc[c], src);
                t = (lane == c) ? tc : t;
            }
            q   = t;
            dnm = fmaxf(rdlane(wsum, src), 1e-6f);
        } else {
            // general path (rare): identical butterfly tree as prior rounds
#pragma unroll
            for (int s2 = 32; s2 >= 1; s2 >>= 1) {
                wsum += __shfl_xor(wsum, s2, 64);
#pragma unroll
                for (int c = 0; c < 16; ++c) acc[c] += __shfl_xor(acc[c], s2, 64);
            }
            float t = acc[0];
#pragma unroll
            for (int c2 = 1; c2 < 16; ++c2) t = (lane == c2) ? acc[c2] : t;
            q = t; dnm = fmaxf(wsum, 1e-6f);
        }

        q = q / dnm;                                   // ONE divide per lane
        // x/y partner (lane^1) via DPP quad_perm [1,0,3,2] -- zero DS ops.
        const float p = __uint_as_float((unsigned)__builtin_amdgcn_update_dpp(
            0, (int)__float_as_uint(q), 0xB1, 0xF, 0xF, true));
        const float detc = (lane >= 16) ? bv
                         : (isx ? (q * m0 + p * m1 + m3) * wf
                                : (p * m4 + q * m5 + m7) * hf);

        if (stuck) {
            // det identical for all remaining rows; lane c holds det[c]
            if (lane < 17) sdet[lane] = detc;
            int n = (MAXD - iter) * 17;
            float* op = ob + iter * 17;
            int c = lane % 17;
            for (int e = lane; e < n; e += 64) {
                op[e] = sdet[c];
                c += 13; if (c >= 17) c -= 17;         // (e+64) % 17
            }
            break;
        } else {
            if (lane < 17) ob[iter * 17 + lane] = detc;
            ++iter;
            if (iter == MAXD) break;
        }
    }
}

// ONE WAVE per batch. Setup (loads, sigmoid, decode, compaction) identical to
// the proven R4/R5/R10 kernel.
__global__ __launch_bounds__(64, 2) void blaze_wave_kernel(
    const float* __restrict__ raw_boxes,   // [B,896,16]
    const float* __restrict__ raw_scores,  // [B,896]
    const float* __restrict__ anchors,     // [896,4]
    const float* __restrict__ tmat,        // [B,8]
    const int* __restrict__ hptr,
    const int* __restrict__ wptr,
    float* __restrict__ out,               // [B,64,17]
    int B)
{
    __shared__ float4 cbox[NANCH];            // compacted decoded boxes
    __shared__ float  cscore[NANCH];          // compacted scores
    __shared__ unsigned short cidx[NANCH];    // compacted -> original anchor idx
    __shared__ float  sdet[17];               // stuck-fill broadcast

    const int lane = threadIdx.x;             // 0..63
    const int b    = blockIdx.x;
    if (b >= B) return;

    const float* rb = raw_boxes  + (size_t)b * (NANCH * 16);
    const float* rs = raw_scores + (size_t)b * NANCH;
    const float inv = 1.f / 128.f;

    // ---- uniform per-batch params in the up-front load burst ----
    const float* M = tmat + (size_t)b * 8;
    const float m0 = M[0], m1 = M[1], m3 = M[3];
    const float m4 = M[4], m5 = M[5], m7 = M[7];
    const float hf = (float)(*hptr);
    const float wf = (float)(*wptr);

    // ---- Phase 1: ALL score loads issued back-to-back ----
    float xv[NS];
#pragma unroll
    for (int j = 0; j < NS; ++j) xv[j] = rs[lane + 64 * j];

    // ---- Phase 2: box/anchor loads gated by SIGN only (sigmoid>=0.5 <=> x>=0;
    //      NaN -> inactive both sides). Inactive lanes alias row 0's line. ----
    bool  act[NS];
    float4 r0v[NS], anv[NS];
#pragma unroll
    for (int j = 0; j < NS; ++j) {
        act[j] = (xv[j] >= 0.f);
        const int a2 = act[j] ? (lane + 64 * j) : 0;
        r0v[j] = *(const float4*)(rb + a2 * 16);
        anv[j] = *(const float4*)(anchors + a2 * 4);
    }

    // ---- sigmoid overlaps the in-flight box loads ----
    float sv[NS];
#pragma unroll
    for (int j = 0; j < NS; ++j) {
        float x = fminf(fmaxf(xv[j], -100.f), 100.f);
        sv[j] = 1.f / (1.f + expf(-x));
    }

    // ---- decode + COMPACT active anchors into LDS (ascending anchor order:
    //      compacted pos is order-isomorphic to anchor index -> exact tiebreak) ----
    int base = 0;
#pragma unroll
    for (int j = 0; j < NS; ++j) {
        float xc = r0v[j].x * inv * anv[j].z + anv[j].x;
        float yc = r0v[j].y * inv * anv[j].w + anv[j].y;
        float ww = r0v[j].z * inv * anv[j].z;
        float hh = r0v[j].w * inv * anv[j].w;
        float y0 = yc - hh * 0.5f, x0 = xc - ww * 0.5f;
        float y1 = yc + hh * 0.5f, x1 = xc + ww * 0.5f;
        unsigned long long m = __ballot(act[j]);
        int pos = base + __popcll(m & ((1ull << lane) - 1ull));
        if (act[j]) {
            cbox[pos]   = make_float4(y0, x0, y1, x1);
            cscore[pos] = sv[j];
            cidx[pos]   = (unsigned short)(lane + 64 * j);
        }
        base += __popcll(m);
    }
    const int nact = base;                  // wave-uniform
    const int nsc  = (nact + 63) >> 6;      // wave-uniform active slot count

    float* ob = out + (size_t)b * (MAXD * 17);

    // ---- one wave-uniform dispatch to a compile-time slot count ----
    if (nsc <= 7)
        nms_loop<7>(lane, nact, cbox, cscore, cidx, sdet, rb, anchors,
                    m0, m1, m3, m4, m5, m7, hf, wf, ob);
    else if (nsc <= 8)
        nms_loop<8>(lane, nact, cbox, cscore, cidx, sdet, rb, anchors,
                    m0, m1, m3, m4, m5, m7, hf, wf, ob);
    else if (nsc <= 10)
        nms_loop<10>(lane, nact, cbox, cscore, cidx, sdet, rb, anchors,
                     m0, m1, m3, m4, m5, m7, hf, wf, ob);
    else
        nms_loop<14>(lane, nact, cbox, cscore, cidx, sdet, rb, anchors,
                     m0, m1, m3, m4, m5, m7, hf, wf, ob);
}

extern "C" void kernel_launch(void* const* d_in, const int* in_sizes, int n_in,
                              void* d_out, int out_size, void* d_ws, size_t ws_size,
                              hipStream_t stream) {
    (void)n_in; (void)out_size; (void)d_ws; (void)ws_size;
    const float* raw_boxes  = (const float*)d_in[0];
    const float* raw_scores = (const float*)d_in[1];
    const float* anchors    = (const float*)d_in[2];
    const float* tmat       = (const float*)d_in[3];
    const int*   hptr       = (const int*)d_in[4];
    const int*   wptr       = (const int*)d_in[5];
    float* out = (float*)d_out;

    const int B = in_sizes[0] / (NANCH * 16);
    blaze_wave_kernel<<<B, 64, 0, stream>>>(raw_boxes, raw_scores, anchors,
                                            tmat, hptr, wptr, out, B);
}